// Round 20
// baseline (71.505 us; speedup 1.0000x reference)
//
#include <hip/hip_runtime.h>

constexpr int IN_H = 384, IN_W = 384;
constexpr int OUT_H = 382, OUT_W = 382;
constexpr int IC = 3, OC = 64, BATCH = 32;

constexpr int LDSW = 400;     // u16 per LDS row (800B)
constexpr int NROW = 30;      // rows rbase..rbase+9 x 3 channels; L = rr*3 + c
constexpr int NBUCKET = 256;  // atomic spread buckets
constexpr int NBLOCKS = 48 * BATCH;   // 1536

constexpr double CLASSICAL_CNT = 298852352.0;   // 32*64*382*382
constexpr double QUANTUM_CNT   = 126078336.0;   // 32*3*382*382*9

typedef short short8 __attribute__((ext_vector_type(8)));
typedef unsigned int u32x4 __attribute__((ext_vector_type(4)));
typedef float f32x4 __attribute__((ext_vector_type(4)));
typedef float f32x2 __attribute__((ext_vector_type(2)));

// sigmoid(z) ~= 0.5 + z*(SC0 + w*(SC1 + w*SC2)), w=z^2, unclamped (validated R15).
#define SC0 0.25f
#define SC1 -0.019993f
#define SC2 0.0012252f

__device__ __forceinline__ unsigned short f2bf(float f) {
    unsigned u = __float_as_uint(f);
    unsigned r = (u + 0x7FFFu + ((u >> 16) & 1u)) >> 16;   // RNE
    return (unsigned short)r;
}

__device__ __forceinline__ unsigned cvt_pk_bf16(float lo, float hi) {
    unsigned d;
    asm("v_cvt_pk_bf16_f32 %0, %1, %2" : "=v"(d) : "v"(lo), "v"(hi));
    return d;
}

// packed fp32 VALU (VOP3P): 2 f32 per instruction (R17 A/B: beats scalar by ~7%)
__device__ __forceinline__ f32x2 pk_mul(f32x2 a, f32x2 b) {
    f32x2 d;
    asm("v_pk_mul_f32 %0, %1, %2" : "=v"(d) : "v"(a), "v"(b));
    return d;
}
__device__ __forceinline__ f32x2 pk_fma(f32x2 a, f32x2 b, f32x2 c) {
    f32x2 d;
    asm("v_pk_fma_f32 %0, %1, %2, %3" : "=v"(d) : "v"(a), "v"(b), "v"(c));
    return d;
}

__device__ __forceinline__ float cospix(float x) {
    float t = 0.5f * x;
    float fr = t - floorf(t);                  // v_fract
    return __builtin_amdgcn_cosf(fr);          // cos(2*pi*fr) = cos(pi*x)
}

// quantum partial for 4 consecutive pixels: uniform ww=3 + edge-column correction
__device__ __forceinline__ float qpart(float4 v, int col4, float wh) {
    float cn0 = cospix(v.x), cn1 = cospix(v.y), cn2 = cospix(v.z), cn3 = cospix(v.w);
    float s4 = (cn0 + cn1) + (cn2 + cn3);
    float corr = 0.0f;
    if (col4 == 0)  corr = 2.0f * cn0 + cn1;   // cols 0,1: ww=1,2
    if (col4 == 95) corr = cn2 + 2.0f * cn3;   // cols 382,383: ww=2,1
    return wh * (3.0f * s4 - corr);
}

__device__ __forceinline__ float whrow(int r) {
    int eh = min(r, 383 - r);
    return (eh < 2) ? (float)(eh + 1) : 3.0f;
}

__device__ __forceinline__ void store_bf4(unsigned short* dst, float4 v) {
    unsigned u0 = cvt_pk_bf16(v.x, v.y);
    unsigned u1 = cvt_pk_bf16(v.z, v.w);
    *(uint2*)dst = uint2{u0, u1};              // ds_write_b64
}

// R20 = R19 data path + 256 buckets + fused last-block combine (no combine dispatch).
__global__ __launch_bounds__(512)
void conv_mfma_kernel(const float* __restrict__ x,
                      const float* __restrict__ Wg,
                      const float* __restrict__ bias,
                      double* __restrict__ acc,
                      float* __restrict__ out)
{
    __shared__ __align__(16) unsigned short xs[NROW * LDSW];   // 24000 B
    __shared__ __align__(16) unsigned short wsB[2048];         // 4096 B
    __shared__ float wsum[8], qsum[8];
    __shared__ double dsum[8], dqsum[8];
    __shared__ unsigned lastflag;

    const int tid = threadIdx.x;
    // XCD-aware swizzle (1536 blocks, %8==0 -> bijective): same image -> same XCD
    const int combined = blockIdx.y * 48 + blockIdx.x;
    const int swz      = (combined & 7) * 192 + (combined >> 3);
    const int b        = swz / 48;
    const int rbase    = (swz - b * 48) * 8;

    const int lane = tid & 63;
    const int wv   = tid >> 6;          // 0..7
    const int lg   = lane >> 4;
    const int lr   = lane & 15;
    const int p    = lr & 1;

    const float* xb = x + (size_t)b * IC * IN_H * IN_W;

    // ---------------- W staging (proven layout), threads 0..255 only ---------------
    if (tid < 256) {
        static constexpr int T0[8] = { 0, 1, 2,  9, 10, 11, 18, 19};  // kh=0
        static constexpr int T1[8] = { 3, 4, 5, 12, 13, 14, 21, 22};  // kh=1
        static constexpr int T2[8] = { 6, 7, 8, 15, 16, 17, 24, 25};  // kh=2
        static constexpr int T3[8] = {20, -2, -1, 23, -1, -1, 26, -1};// leftovers + BIAS at i=1
        const int lgw = (tid >> 4) & 3;
        const int oc  = ((tid >> 6) << 4) + (tid & 15);   // j*16 + lr
        unsigned short w8[8];
        #pragma unroll
        for (int i = 0; i < 8; ++i) {
            int s = (lgw == 0) ? T0[i] : (lgw == 1) ? T1[i] : (lgw == 2) ? T2[i] : T3[i];
            float w = 0.0f;
            if (s >= 0)       w = Wg[oc * 27 + s];
            else if (s == -2) w = bias[oc];
            w8[i] = f2bf(w);
        }
        u32x4 pk;
        pk[0] = (unsigned)w8[0] | ((unsigned)w8[1] << 16);
        pk[1] = (unsigned)w8[2] | ((unsigned)w8[3] << 16);
        pk[2] = (unsigned)w8[4] | ((unsigned)w8[5] << 16);
        pk[3] = (unsigned)w8[6] | ((unsigned)w8[7] << 16);
        *(u32x4*)&wsB[tid * 8] = pk;
    }

    // ---------------- zero LDS col pads 384..399 on all 30 rows --------------------
    if (tid < NROW * 16) xs[(tid >> 4) * LDSW + 384 + (tid & 15)] = 0;

    float q_local = 0.0f;

    // ---------------- stage rows rbase..rbase+9 (quantum-owned: rr<8) --------------
    #pragma unroll
    for (int k = 0; k < 6; ++k) {
        int e = tid + k * 512;
        if (e < 2880) {
            int rr   = e / 288;                          // 0..9
            int rem  = e - rr * 288;
            int c    = rem / 96;
            int col4 = rem - c * 96;
            int row  = min(rbase + rr, 383);             // clamp matters only for last block
            float4 v = ((const float4*)(xb + ((size_t)c * IN_H + row) * IN_W))[col4];
            if (rr < 8) q_local += qpart(v, col4, whrow(row));   // row == rbase+rr here
            store_bf4(&xs[(rr * 3 + c) * LDSW + col4 * 4], v);
        }
    }
    __syncthreads();

    // ---------------- per-lane fragments & constants --------------------------------
    short8 bfrag[4];
    #pragma unroll
    for (int j = 0; j < 4; ++j)
        bfrag[j] = *(const short8*)&wsB[(((j * 4 + lg) * 16) + lr) * 8];

    const unsigned sel1 = p ? 0x03020706u : 0x01000504u;
    const unsigned sel3 = p ? 0x05040302u : 0x03020100u;
    const int sh0 = 16 * p;
    const int sh2 = 16 * p + 16;
    const bool g3 = (lg == 3);
    const int cA = g3 ? 2 : 0, khA = g3 ? 0 : lg;
    const int cB = g3 ? 2 : 1, khB = g3 ? 1 : lg;
    const int cC = 2,          khC = g3 ? 2 : lg;
    const int eoff = g3 ? 1 : 0;
    const int lrh  = lr >> 1;
    const unsigned dsel = g3 ? 0x03020504u : 0x07060504u;  // v_perm bias inject
    const unsigned K1   = 0x3F800000u;

    // edge-strip masks (pixel col = 368 + lg*4 + t, valid iff lg*4+t < 14)
    f32x2 mlo = { (lg * 4 + 0 < 14) ? 1.0f : 0.0f, (lg * 4 + 1 < 14) ? 1.0f : 0.0f };
    f32x2 mhi = { (lg * 4 + 2 < 14) ? 1.0f : 0.0f, (lg * 4 + 3 < 14) ? 1.0f : 0.0f };

    const f32x2 sc2 = {SC2, SC2}, sc1 = {SC1, SC1}, sc0 = {SC0, SC0};

    const unsigned* xw = (const unsigned*)xs;
    const f32x4 zero4 = {0.0f, 0.0f, 0.0f, 0.0f};
    f32x2 acc_lo = {0.0f, 0.0f}, acc_hi = {0.0f, 0.0f};

    // ---------------- compute: wave wv owns output row rbase+wv --------------------
    const int oh = rbase + wv;
    if (oh < OUT_H) {
        const int baseA = ((wv + khA) * 3 + cA) * 200 + lrh + eoff;
        const int baseB = ((wv + khB) * 3 + cB) * 200 + lrh + eoff;
        const int baseC = ((wv + khC) * 3 + cC) * 200 + lrh + eoff;

        auto gather = [&](int cs) -> short8 {
            unsigned A0 = xw[baseA + 8 * cs], A1 = xw[baseA + 8 * cs + 1];
            unsigned B0 = xw[baseB + 8 * cs], B1 = xw[baseB + 8 * cs + 1];
            unsigned C0 = xw[baseC + 8 * cs], C1 = xw[baseC + 8 * cs + 1];
            unsigned F  = (unsigned)(((unsigned long long)A1 << 32 | A0) >> sh0);
            unsigned D0 = __builtin_amdgcn_perm(F, K1, dsel);   // bias row: af[1]=1.0
            unsigned D1 = __builtin_amdgcn_perm(A1, B0, sel1);
            unsigned D2 = (unsigned)(((unsigned long long)B1 << 32 | B0) >> sh2);
            unsigned D3 = __builtin_amdgcn_perm(C1, C0, sel3);
            return __builtin_bit_cast(short8, u32x4{D0, D1, D2, D3});
        };

        f32x4 zp0, zp1, zp2, zp3;
        auto mfma4 = [&](const short8& af) {
            zp0 = __builtin_amdgcn_mfma_f32_16x16x32_bf16(af, bfrag[0], zero4, 0, 0, 0);
            zp1 = __builtin_amdgcn_mfma_f32_16x16x32_bf16(af, bfrag[1], zero4, 0, 0, 0);
            zp2 = __builtin_amdgcn_mfma_f32_16x16x32_bf16(af, bfrag[2], zero4, 0, 0, 0);
            zp3 = __builtin_amdgcn_mfma_f32_16x16x32_bf16(af, bfrag[3], zero4, 0, 0, 0);
        };
        auto poly4 = [&](const f32x4& z) {              // quad: 8 pk per 4 outputs
            f32x2 zlo = {z[0], z[1]}, zhi = {z[2], z[3]};
            f32x2 wlo = pk_mul(zlo, zlo), whi = pk_mul(zhi, zhi);
            f32x2 plo = pk_fma(wlo, sc2, sc1), phi = pk_fma(whi, sc2, sc1);
            plo = pk_fma(wlo, plo, sc0);  phi = pk_fma(whi, phi, sc0);
            acc_lo = pk_fma(zlo, plo, acc_lo);
            acc_hi = pk_fma(zhi, phi, acc_hi);
        };
        auto poly4m = [&](const f32x4& z) {
            f32x2 zlo = {z[0], z[1]}, zhi = {z[2], z[3]};
            f32x2 wlo = pk_mul(zlo, zlo), whi = pk_mul(zhi, zhi);
            f32x2 plo = pk_fma(wlo, sc2, sc1), phi = pk_fma(whi, sc2, sc1);
            plo = pk_fma(wlo, plo, sc0);  phi = pk_fma(whi, phi, sc0);
            f32x2 tlo = pk_mul(zlo, plo), thi = pk_mul(zhi, phi);
            acc_lo = pk_fma(mlo, tlo, acc_lo);
            acc_hi = pk_fma(mhi, thi, acc_hi);
        };

        // distance-2 pipeline (compiler refines)
        mfma4(gather(0));
        short8 af2 = gather(1);

        #pragma unroll
        for (int cs = 0; cs < 22; ++cs) {
            short8 afn = gather(cs + 2);
            poly4(zp0); poly4(zp1); poly4(zp2); poly4(zp3);   // strip cs (interior)
            mfma4(af2);
            af2 = afn;
        }
        poly4(zp0); poly4(zp1); poly4(zp2); poly4(zp3);       // strip 22
        mfma4(af2);
        poly4m(zp0); poly4m(zp1); poly4m(zp2); poly4m(zp3);   // strip 23 (edge)
    }

    // ---------------- block reduction + spread atomic ---------------------------------
    float th = (acc_lo[0] + acc_lo[1]) + (acc_hi[0] + acc_hi[1]);
    #pragma unroll
    for (int off = 32; off > 0; off >>= 1) {
        th      += __shfl_down(th, off);
        q_local += __shfl_down(q_local, off);
    }

    if (lane == 0) { wsum[wv] = th; qsum[wv] = q_local; }
    __syncthreads();
    if (tid == 0) {
        float ssum = 0.0f, qq = 0.0f;
        #pragma unroll
        for (int i = 0; i < 8; ++i) { ssum += wsum[i]; qq += qsum[i]; }
        // 256-bucket spread: adjacent blocks hit distinct lines
        double* bucket = acc + 2 * (combined & (NBUCKET - 1));
        atomicAdd(bucket,     (double)ssum);
        atomicAdd(bucket + 1, (double)qq);
        __threadfence();                         // release bucket adds before counter
        unsigned* cnt = (unsigned*)(acc + 2 * NBUCKET);
        unsigned prev = atomicAdd(cnt, 1u);
        lastflag = (prev == NBLOCKS - 1) ? 1u : 0u;
    }
    __syncthreads();

    // ---------------- fused combine: last block reduces the buckets ----------------
    if (lastflag) {
        // 512 threads: thread t owns double index t; device-scope atomic read
        // (atomicAdd +0.0) bypasses non-coherent local L2.
        double v = atomicAdd(&acc[tid], 0.0);
        double cv = (tid & 1) ? 0.0 : v;       // even idx = classical
        double qv = (tid & 1) ? v   : 0.0;     // odd idx = quantum
        #pragma unroll
        for (int off = 32; off > 0; off >>= 1) {
            cv += __shfl_down(cv, off);
            qv += __shfl_down(qv, off);
        }
        if (lane == 0) { dsum[wv] = cv; dqsum[wv] = qv; }
        __syncthreads();
        if (tid == 0) {
            double cs = 0.0, qs = 0.0;
            #pragma unroll
            for (int i = 0; i < 8; ++i) { cs += dsum[i]; qs += dqsum[i]; }
            const double cterm = cs / CLASSICAL_CNT;   // sum of z*P(z), bias inside z
            const double qterm = qs / QUANTUM_CNT;     // weighted mean of cos(pi x)
            out[0] = (float)(0.5 + 0.5 * cterm - 0.25 * qterm);
        }
    }
}

extern "C" void kernel_launch(void* const* d_in, const int* in_sizes, int n_in,
                              void* d_out, int out_size, void* d_ws, size_t ws_size,
                              hipStream_t stream)
{
    const float* x  = (const float*)d_in[0];
    const float* W  = (const float*)d_in[1];
    const float* b  = (const float*)d_in[2];
    float* out      = (float*)d_out;
    double* acc     = (double*)d_ws;

    // zero 256 bucket pairs + completion counter (deterministic per call)
    (void)hipMemsetAsync(acc, 0, (2 * NBUCKET + 2) * sizeof(double), stream);

    dim3 grid(48, BATCH);   // 48 row-blocks of 8 output rows x 32 batches
    conv_mfma_kernel<<<grid, 512, 0, stream>>>(x, W, b, acc, out);
}

// Round 21
// 56.597 us; speedup vs baseline: 1.2634x; 1.2634x over previous
//
#include <hip/hip_runtime.h>

constexpr int IN_H = 384, IN_W = 384;
constexpr int OUT_H = 382, OUT_W = 382;
constexpr int IC = 3, OC = 64, BATCH = 32;

constexpr int LDSW = 400;   // u16 per LDS row (800B)
constexpr int NROW = 30;    // rows rbase..rbase+9 x 3 channels; L = rr*3 + c
constexpr int NBUCKET = 64; // atomic spread buckets

constexpr double CLASSICAL_CNT = 298852352.0;   // 32*64*382*382
constexpr double QUANTUM_CNT   = 126078336.0;   // 32*3*382*382*9

typedef short short8 __attribute__((ext_vector_type(8)));
typedef unsigned int u32x4 __attribute__((ext_vector_type(4)));
typedef float f32x4 __attribute__((ext_vector_type(4)));
typedef float f32x2 __attribute__((ext_vector_type(2)));

// sigmoid(z) ~= 0.5 + z*(SC0 + w*(SC1 + w*SC2)), w=z^2, unclamped (validated R15).
#define SC0 0.25f
#define SC1 -0.019993f
#define SC2 0.0012252f

__device__ __forceinline__ unsigned short f2bf(float f) {
    unsigned u = __float_as_uint(f);
    unsigned r = (u + 0x7FFFu + ((u >> 16) & 1u)) >> 16;   // RNE
    return (unsigned short)r;
}

__device__ __forceinline__ unsigned cvt_pk_bf16(float lo, float hi) {
    unsigned d;
    asm("v_cvt_pk_bf16_f32 %0, %1, %2" : "=v"(d) : "v"(lo), "v"(hi));
    return d;
}

// packed fp32 VALU (VOP3P): 2 f32 per instruction (R17 A/B: beats scalar by ~7%)
__device__ __forceinline__ f32x2 pk_mul(f32x2 a, f32x2 b) {
    f32x2 d;
    asm("v_pk_mul_f32 %0, %1, %2" : "=v"(d) : "v"(a), "v"(b));
    return d;
}
__device__ __forceinline__ f32x2 pk_fma(f32x2 a, f32x2 b, f32x2 c) {
    f32x2 d;
    asm("v_pk_fma_f32 %0, %1, %2, %3" : "=v"(d) : "v"(a), "v"(b), "v"(c));
    return d;
}

__device__ __forceinline__ float cospix(float x) {
    float t = 0.5f * x;
    float fr = t - floorf(t);                  // v_fract
    return __builtin_amdgcn_cosf(fr);          // cos(2*pi*fr) = cos(pi*x)
}

// quantum partial for 4 consecutive pixels: uniform ww=3 + edge-column correction
__device__ __forceinline__ float qpart(float4 v, int col4, float wh) {
    float cn0 = cospix(v.x), cn1 = cospix(v.y), cn2 = cospix(v.z), cn3 = cospix(v.w);
    float s4 = (cn0 + cn1) + (cn2 + cn3);
    float corr = 0.0f;
    if (col4 == 0)  corr = 2.0f * cn0 + cn1;   // cols 0,1: ww=1,2
    if (col4 == 95) corr = cn2 + 2.0f * cn3;   // cols 382,383: ww=2,1
    return wh * (3.0f * s4 - corr);
}

__device__ __forceinline__ float whrow(int r) {
    int eh = min(r, 383 - r);
    return (eh < 2) ? (float)(eh + 1) : 3.0f;
}

__device__ __forceinline__ void store_bf4(unsigned short* dst, float4 v) {
    unsigned u0 = cvt_pk_bf16(v.x, v.y);
    unsigned u1 = cvt_pk_bf16(v.z, v.w);
    *(uint2*)dst = uint2{u0, u1};              // ds_write_b64
}

// R21 = R19 verbatim (best verified: 56.6 us). 512 thr (8 waves), 8 output rows,
// one stage phase + one barrier, distance-2 strip pipeline, asm-pk quad poly,
// 64-bucket atomic spread + tiny combine dispatch (R20's fused fence was -15 us).
__global__ __launch_bounds__(512)
void conv_mfma_kernel(const float* __restrict__ x,
                      const float* __restrict__ Wg,
                      const float* __restrict__ bias,
                      double* __restrict__ acc)
{
    __shared__ __align__(16) unsigned short xs[NROW * LDSW];   // 24000 B
    __shared__ __align__(16) unsigned short wsB[2048];         // 4096 B
    __shared__ float wsum[8], qsum[8];

    const int tid = threadIdx.x;
    // XCD-aware swizzle (1536 blocks, %8==0 -> bijective): same image -> same XCD
    const int combined = blockIdx.y * 48 + blockIdx.x;
    const int swz      = (combined & 7) * 192 + (combined >> 3);
    const int b        = swz / 48;
    const int rbase    = (swz - b * 48) * 8;

    const int lane = tid & 63;
    const int wv   = tid >> 6;          // 0..7
    const int lg   = lane >> 4;
    const int lr   = lane & 15;
    const int p    = lr & 1;

    const float* xb = x + (size_t)b * IC * IN_H * IN_W;

    // ---------------- W staging (proven layout), threads 0..255 only ---------------
    if (tid < 256) {
        static constexpr int T0[8] = { 0, 1, 2,  9, 10, 11, 18, 19};  // kh=0
        static constexpr int T1[8] = { 3, 4, 5, 12, 13, 14, 21, 22};  // kh=1
        static constexpr int T2[8] = { 6, 7, 8, 15, 16, 17, 24, 25};  // kh=2
        static constexpr int T3[8] = {20, -2, -1, 23, -1, -1, 26, -1};// leftovers + BIAS at i=1
        const int lgw = (tid >> 4) & 3;
        const int oc  = ((tid >> 6) << 4) + (tid & 15);   // j*16 + lr
        unsigned short w8[8];
        #pragma unroll
        for (int i = 0; i < 8; ++i) {
            int s = (lgw == 0) ? T0[i] : (lgw == 1) ? T1[i] : (lgw == 2) ? T2[i] : T3[i];
            float w = 0.0f;
            if (s >= 0)       w = Wg[oc * 27 + s];
            else if (s == -2) w = bias[oc];
            w8[i] = f2bf(w);
        }
        u32x4 pk;
        pk[0] = (unsigned)w8[0] | ((unsigned)w8[1] << 16);
        pk[1] = (unsigned)w8[2] | ((unsigned)w8[3] << 16);
        pk[2] = (unsigned)w8[4] | ((unsigned)w8[5] << 16);
        pk[3] = (unsigned)w8[6] | ((unsigned)w8[7] << 16);
        *(u32x4*)&wsB[tid * 8] = pk;
    }

    // ---------------- zero LDS col pads 384..399 on all 30 rows --------------------
    if (tid < NROW * 16) xs[(tid >> 4) * LDSW + 384 + (tid & 15)] = 0;

    float q_local = 0.0f;

    // ---------------- stage rows rbase..rbase+9 (quantum-owned: rr<8) --------------
    #pragma unroll
    for (int k = 0; k < 6; ++k) {
        int e = tid + k * 512;
        if (e < 2880) {
            int rr   = e / 288;                          // 0..9
            int rem  = e - rr * 288;
            int c    = rem / 96;
            int col4 = rem - c * 96;
            int row  = min(rbase + rr, 383);             // clamp matters only for last block
            float4 v = ((const float4*)(xb + ((size_t)c * IN_H + row) * IN_W))[col4];
            if (rr < 8) q_local += qpart(v, col4, whrow(row));   // row == rbase+rr here
            store_bf4(&xs[(rr * 3 + c) * LDSW + col4 * 4], v);
        }
    }
    __syncthreads();

    // ---------------- per-lane fragments & constants --------------------------------
    short8 bfrag[4];
    #pragma unroll
    for (int j = 0; j < 4; ++j)
        bfrag[j] = *(const short8*)&wsB[(((j * 4 + lg) * 16) + lr) * 8];

    const unsigned sel1 = p ? 0x03020706u : 0x01000504u;
    const unsigned sel3 = p ? 0x05040302u : 0x03020100u;
    const int sh0 = 16 * p;
    const int sh2 = 16 * p + 16;
    const bool g3 = (lg == 3);
    const int cA = g3 ? 2 : 0, khA = g3 ? 0 : lg;
    const int cB = g3 ? 2 : 1, khB = g3 ? 1 : lg;
    const int cC = 2,          khC = g3 ? 2 : lg;
    const int eoff = g3 ? 1 : 0;
    const int lrh  = lr >> 1;
    const unsigned dsel = g3 ? 0x03020504u : 0x07060504u;  // v_perm bias inject
    const unsigned K1   = 0x3F800000u;

    // edge-strip masks (pixel col = 368 + lg*4 + t, valid iff lg*4+t < 14)
    f32x2 mlo = { (lg * 4 + 0 < 14) ? 1.0f : 0.0f, (lg * 4 + 1 < 14) ? 1.0f : 0.0f };
    f32x2 mhi = { (lg * 4 + 2 < 14) ? 1.0f : 0.0f, (lg * 4 + 3 < 14) ? 1.0f : 0.0f };

    const f32x2 sc2 = {SC2, SC2}, sc1 = {SC1, SC1}, sc0 = {SC0, SC0};

    const unsigned* xw = (const unsigned*)xs;
    const f32x4 zero4 = {0.0f, 0.0f, 0.0f, 0.0f};
    f32x2 acc_lo = {0.0f, 0.0f}, acc_hi = {0.0f, 0.0f};

    // ---------------- compute: wave wv owns output row rbase+wv --------------------
    const int oh = rbase + wv;
    if (oh < OUT_H) {
        const int baseA = ((wv + khA) * 3 + cA) * 200 + lrh + eoff;
        const int baseB = ((wv + khB) * 3 + cB) * 200 + lrh + eoff;
        const int baseC = ((wv + khC) * 3 + cC) * 200 + lrh + eoff;

        auto gather = [&](int cs) -> short8 {
            unsigned A0 = xw[baseA + 8 * cs], A1 = xw[baseA + 8 * cs + 1];
            unsigned B0 = xw[baseB + 8 * cs], B1 = xw[baseB + 8 * cs + 1];
            unsigned C0 = xw[baseC + 8 * cs], C1 = xw[baseC + 8 * cs + 1];
            unsigned F  = (unsigned)(((unsigned long long)A1 << 32 | A0) >> sh0);
            unsigned D0 = __builtin_amdgcn_perm(F, K1, dsel);   // bias row: af[1]=1.0
            unsigned D1 = __builtin_amdgcn_perm(A1, B0, sel1);
            unsigned D2 = (unsigned)(((unsigned long long)B1 << 32 | B0) >> sh2);
            unsigned D3 = __builtin_amdgcn_perm(C1, C0, sel3);
            return __builtin_bit_cast(short8, u32x4{D0, D1, D2, D3});
        };

        f32x4 zp0, zp1, zp2, zp3;
        auto mfma4 = [&](const short8& af) {
            zp0 = __builtin_amdgcn_mfma_f32_16x16x32_bf16(af, bfrag[0], zero4, 0, 0, 0);
            zp1 = __builtin_amdgcn_mfma_f32_16x16x32_bf16(af, bfrag[1], zero4, 0, 0, 0);
            zp2 = __builtin_amdgcn_mfma_f32_16x16x32_bf16(af, bfrag[2], zero4, 0, 0, 0);
            zp3 = __builtin_amdgcn_mfma_f32_16x16x32_bf16(af, bfrag[3], zero4, 0, 0, 0);
        };
        auto poly4 = [&](const f32x4& z) {              // quad: 8 pk per 4 outputs
            f32x2 zlo = {z[0], z[1]}, zhi = {z[2], z[3]};
            f32x2 wlo = pk_mul(zlo, zlo), whi = pk_mul(zhi, zhi);
            f32x2 plo = pk_fma(wlo, sc2, sc1), phi = pk_fma(whi, sc2, sc1);
            plo = pk_fma(wlo, plo, sc0);  phi = pk_fma(whi, phi, sc0);
            acc_lo = pk_fma(zlo, plo, acc_lo);
            acc_hi = pk_fma(zhi, phi, acc_hi);
        };
        auto poly4m = [&](const f32x4& z) {
            f32x2 zlo = {z[0], z[1]}, zhi = {z[2], z[3]};
            f32x2 wlo = pk_mul(zlo, zlo), whi = pk_mul(zhi, zhi);
            f32x2 plo = pk_fma(wlo, sc2, sc1), phi = pk_fma(whi, sc2, sc1);
            plo = pk_fma(wlo, plo, sc0);  phi = pk_fma(whi, phi, sc0);
            f32x2 tlo = pk_mul(zlo, plo), thi = pk_mul(zhi, phi);
            acc_lo = pk_fma(mlo, tlo, acc_lo);
            acc_hi = pk_fma(mhi, thi, acc_hi);
        };

        // distance-2 pipeline (compiler refines)
        mfma4(gather(0));
        short8 af2 = gather(1);

        #pragma unroll
        for (int cs = 0; cs < 22; ++cs) {
            short8 afn = gather(cs + 2);
            poly4(zp0); poly4(zp1); poly4(zp2); poly4(zp3);   // strip cs (interior)
            mfma4(af2);
            af2 = afn;
        }
        poly4(zp0); poly4(zp1); poly4(zp2); poly4(zp3);       // strip 22
        mfma4(af2);
        poly4m(zp0); poly4m(zp1); poly4m(zp2); poly4m(zp3);   // strip 23 (edge)
    }

    // ---------------- reduction -----------------------------------------------------
    float th = (acc_lo[0] + acc_lo[1]) + (acc_hi[0] + acc_hi[1]);
    #pragma unroll
    for (int off = 32; off > 0; off >>= 1) {
        th      += __shfl_down(th, off);
        q_local += __shfl_down(q_local, off);
    }

    if (lane == 0) { wsum[wv] = th; qsum[wv] = q_local; }
    __syncthreads();
    if (tid == 0) {
        float ssum = 0.0f, qq = 0.0f;
        #pragma unroll
        for (int i = 0; i < 8; ++i) { ssum += wsum[i]; qq += qsum[i]; }
        // 64-bucket spread: adjacent blocks hit distinct lines (bucket = combined & 63)
        double* bucket = acc + 2 * (combined & (NBUCKET - 1));
        atomicAdd(bucket,     (double)ssum);
        atomicAdd(bucket + 1, (double)qq);
    }
}

__global__ void combine_kernel(const double* __restrict__ acc, float* __restrict__ out)
{
    // one wave: lane i owns bucket i; shuffle-reduce 64 buckets
    const int lane = threadIdx.x & 63;
    double cs = acc[2 * lane];
    double qs = acc[2 * lane + 1];
    #pragma unroll
    for (int off = 32; off > 0; off >>= 1) {
        cs += __shfl_down(cs, off);
        qs += __shfl_down(qs, off);
    }
    if (lane == 0) {
        const double cterm = cs / CLASSICAL_CNT;   // sum of z*P(z), bias inside z
        const double qterm = qs / QUANTUM_CNT;     // weighted mean of cos(pi x)
        out[0] = (float)(0.5 + 0.5 * cterm - 0.25 * qterm);
    }
}

extern "C" void kernel_launch(void* const* d_in, const int* in_sizes, int n_in,
                              void* d_out, int out_size, void* d_ws, size_t ws_size,
                              hipStream_t stream)
{
    const float* x  = (const float*)d_in[0];
    const float* W  = (const float*)d_in[1];
    const float* b  = (const float*)d_in[2];
    float* out      = (float*)d_out;
    double* acc     = (double*)d_ws;

    (void)hipMemsetAsync(acc, 0, 2 * NBUCKET * sizeof(double), stream);

    dim3 grid(48, BATCH);   // 48 row-blocks of 8 output rows x 32 batches
    conv_mfma_kernel<<<grid, 512, 0, stream>>>(x, W, b, acc);
    combine_kernel<<<1, 64, 0, stream>>>(acc, out);
}